// Round 1
// baseline (788.122 us; speedup 1.0000x reference)
//
#include <hip/hip_runtime.h>
#include <cstdint>
#include <cstddef>

#define N 8192
#define DIN 128
#define DTH 256
#define DOUT 128
#define ROWCAP 256
#define LISTCAP 1024

// ---------------- threefry2x32 with key (0, 42) --------------------------
__device__ __forceinline__ void threefry_0_42(uint32_t x0, uint32_t x1,
                                              uint32_t& o0, uint32_t& o1) {
  const uint32_t ks0 = 0u;
  const uint32_t ks1 = 42u;
  const uint32_t ks2 = 0x1BD11BDAu ^ 0u ^ 42u;
  x0 += ks0; x1 += ks1;
#define TF_R(r) { x0 += x1; x1 = (x1 << (r)) | (x1 >> (32 - (r))); x1 ^= x0; }
  TF_R(13) TF_R(15) TF_R(26) TF_R(6)
  x0 += ks1; x1 += ks2 + 1u;
  TF_R(17) TF_R(29) TF_R(16) TF_R(24)
  x0 += ks2; x1 += ks0 + 2u;
  TF_R(13) TF_R(15) TF_R(26) TF_R(6)
  x0 += ks0; x1 += ks1 + 3u;
  TF_R(17) TF_R(29) TF_R(16) TF_R(24)
  x0 += ks1; x1 += ks2 + 4u;
  TF_R(13) TF_R(15) TF_R(26) TF_R(6)
  x0 += ks2; x1 += ks0 + 5u;
#undef TF_R
  o0 = x0; o1 = x1;
}

// keep-bit for upper-tri flat index t (partitionable threefry, JAX >= 0.4.36)
__device__ __forceinline__ bool dropedge_keep(uint32_t t) {
  uint32_t y0, y1;
  threefry_0_42(0u, t, y0, y1);
  uint32_t bits = y0 ^ y1;
  float u = __uint_as_float((bits >> 9) | 0x3f800000u) - 1.0f;
  return u < 0.8f;
}

// ---------------- K1: BN stats -> scale/shift ----------------------------
__global__ void k_bn_stats(const float* __restrict__ H,
                           const float* __restrict__ gamma,
                           const float* __restrict__ beta,
                           float* __restrict__ scale,
                           float* __restrict__ shift) {
  __shared__ float red0[256];
  __shared__ float red1[256];
  int c = blockIdx.x;       // 0..127
  int tid = threadIdx.x;    // 256
  float s = 0.f, s2 = 0.f;
  for (int r = tid; r < N; r += 256) {
    float v = H[(size_t)r * DIN + c];
    s += v; s2 += v * v;
  }
  red0[tid] = s; red1[tid] = s2;
  __syncthreads();
  for (int off = 128; off > 0; off >>= 1) {
    if (tid < off) { red0[tid] += red0[tid + off]; red1[tid] += red1[tid + off]; }
    __syncthreads();
  }
  if (tid == 0) {
    float mean = red0[0] * (1.0f / N);
    float var  = red1[0] * (1.0f / N) - mean * mean;
    float sc = rsqrtf(var + 1e-5f) * gamma[c];
    scale[c] = sc;
    shift[c] = beta[c] - mean * sc;
  }
}

// ---------------- K2: per-row Hn, Hx, sq, HW -----------------------------
__global__ __launch_bounds__(256) void k_rows(
    const float* __restrict__ H, const float* __restrict__ scale,
    const float* __restrict__ shift,
    const float* __restrict__ Wt, const float* __restrict__ bt,
    const float* __restrict__ Wo, const float* __restrict__ bo,
    float* __restrict__ Hx, float* __restrict__ sq, float* __restrict__ HW) {
  __shared__ float hn[DIN];
  __shared__ float red[256];
  int i = blockIdx.x;
  int tid = threadIdx.x;    // 256
  if (tid < DIN) {
    float v = H[(size_t)i * DIN + tid];
    hn[tid] = v * scale[tid] + shift[tid];
  }
  __syncthreads();
  // Hx[i][tid]
  {
    const float4* w = (const float4*)(Wt + (size_t)tid * DIN);
    float dot = 0.f;
#pragma unroll
    for (int c4 = 0; c4 < DIN / 4; ++c4) {
      float4 wv = w[c4];
      dot += wv.x * hn[c4*4+0] + wv.y * hn[c4*4+1]
           + wv.z * hn[c4*4+2] + wv.w * hn[c4*4+3];
    }
    float hx = dot + bt[tid];
    Hx[(size_t)i * DTH + tid] = hx;
    red[tid] = hx * hx;
  }
  __syncthreads();
  for (int off = 128; off > 0; off >>= 1) {
    if (tid < off) red[tid] += red[tid + off];
    __syncthreads();
  }
  if (tid == 0) sq[i] = red[0];
  // HW[i][tid]
  if (tid < DOUT) {
    const float4* w = (const float4*)(Wo + (size_t)tid * DIN);
    float dot = 0.f;
#pragma unroll
    for (int c4 = 0; c4 < DIN / 4; ++c4) {
      float4 wv = w[c4];
      dot += wv.x * hn[c4*4+0] + wv.y * hn[c4*4+1]
           + wv.z * hn[c4*4+2] + wv.w * hn[c4*4+3];
    }
    HW[(size_t)i * DOUT + tid] = dot + bo[tid];
  }
}

// ---------------- K3: N^2 pass, sparse on adjacency ----------------------
__global__ __launch_bounds__(256) void k_adj(
    const float* __restrict__ A_adj, const float* __restrict__ Hx,
    const float* __restrict__ sq, float* __restrict__ A3,
    float* __restrict__ deg, int* __restrict__ nnz_cnt,
    int* __restrict__ nnz_idx, float* __restrict__ nnz_val) {
  __shared__ float hx_i[DTH];
  __shared__ int   s_list[LISTCAP];
  __shared__ int   s_cnt;
  __shared__ float s_deg;
  __shared__ int   s_nnz;
  int i = blockIdx.x;
  int tid = threadIdx.x;    // 256
  if (tid == 0) { s_cnt = 0; s_deg = 0.f; s_nnz = 0; }
  if (tid < DTH) hx_i[tid] = Hx[(size_t)i * DTH + tid];
  __syncthreads();

  const size_t rowoff = (size_t)i * N;
  const float4* arow = (const float4*)(A_adj + rowoff);
  float4* a3row4 = (float4*)(A3 + rowoff);
  // phase 1: zero-fill zeros, compact nonzero columns
  for (int it = 0; it < N / 4 / 256; ++it) {   // 8 iters
    int j4 = tid + it * 256;
    float4 a = arow[j4];
    if (a.x == 0.f && a.y == 0.f && a.z == 0.f && a.w == 0.f) {
      a3row4[j4] = make_float4(0.f, 0.f, 0.f, 0.f);
    } else {
      int j = j4 * 4;
      float av[4] = {a.x, a.y, a.z, a.w};
#pragma unroll
      for (int q = 0; q < 4; ++q) {
        if (av[q] != 0.f) {
          int p = atomicAdd(&s_cnt, 1);
          if (p < LISTCAP) s_list[p] = j + q;
        } else {
          A3[rowoff + j + q] = 0.f;
        }
      }
    }
  }
  __syncthreads();
  int M = s_cnt; if (M > LISTCAP) M = LISTCAP;
  float sqi = sq[i];
  // phase 2: expensive work only on adjacency positions
  for (int t = tid; t < M; t += 256) {
    int j = s_list[t];
    uint32_t r = (uint32_t)min(i, j), c = (uint32_t)max(i, j);
    bool keep = dropedge_keep(r * (uint32_t)N + c);
    const float4* hj = (const float4*)(Hx + (size_t)j * DTH);
    float dot = 0.f;
#pragma unroll 8
    for (int c4 = 0; c4 < DTH / 4; ++c4) {
      float4 h = hj[c4];
      dot += h.x * hx_i[c4*4+0] + h.y * hx_i[c4*4+1]
           + h.z * hx_i[c4*4+2] + h.w * hx_i[c4*4+3];
    }
    float dist = sqi + sq[j] - 2.0f * dot;
    dist = sqrtf(fmaxf(dist, 1e-12f));
    float aval = __expf(0.f) * 0.f + expf(-0.2f * dist);
    float sg = 1.0f / (1.0f + expf(-aval));
    sg = fmaxf(sg, 0.1f);
    float b = keep ? sg : 0.0f;
    float a2 = b + ((i == j) ? 1.0f : 0.0f);
    float a3v = (a2 > 0.6f) ? a2 : 0.0f;
    A3[rowoff + j] = a3v;
    if (a3v != 0.f) {
      atomicAdd(&s_deg, a3v);
      int p = atomicAdd(&s_nnz, 1);
      if (p < ROWCAP) {
        nnz_idx[(size_t)i * ROWCAP + p] = j;
        nnz_val[(size_t)i * ROWCAP + p] = a3v;
      }
    }
  }
  __syncthreads();
  if (tid == 0) { deg[i] = s_deg; nnz_cnt[i] = min(s_nnz, ROWCAP); }
}

// ---------------- K4: out = lrelu(D^-1/2 A3 D^-1/2 @ HW) -----------------
__global__ __launch_bounds__(128) void k_out(
    const float* __restrict__ HW, const float* __restrict__ deg,
    const int* __restrict__ nnz_cnt, const int* __restrict__ nnz_idx,
    const float* __restrict__ nnz_val, float* __restrict__ out) {
  int i = blockIdx.x;
  int c = threadIdx.x;      // 128
  int cnt = nnz_cnt[i];
  float acc = 0.f;
  for (int e = 0; e < cnt; ++e) {
    int j = nnz_idx[(size_t)i * ROWCAP + e];
    float v = nnz_val[(size_t)i * ROWCAP + e];
    acc += v * rsqrtf(deg[j]) * HW[(size_t)j * DOUT + c];
  }
  float o = rsqrtf(deg[i]) * acc;
  out[(size_t)i * DOUT + c] = (o >= 0.f) ? o : 0.01f * o;
}

// ---------------- launch --------------------------------------------------
extern "C" void kernel_launch(void* const* d_in, const int* in_sizes, int n_in,
                              void* d_out, int out_size, void* d_ws, size_t ws_size,
                              hipStream_t stream) {
  const float* H     = (const float*)d_in[0];
  const float* A_adj = (const float*)d_in[1];
  const float* gamma = (const float*)d_in[2];
  const float* beta  = (const float*)d_in[3];
  const float* Wt    = (const float*)d_in[4];
  const float* bt    = (const float*)d_in[5];
  const float* Wo    = (const float*)d_in[6];
  const float* bo    = (const float*)d_in[7];

  float* out = (float*)d_out;                    // [N, DOUT]
  float* A3  = out + (size_t)N * DOUT;           // [N, N]

  float* ws    = (float*)d_ws;
  float* scale = ws;                              // 128
  float* shift = ws + 128;                        // 128
  float* Hx    = ws + 256;                        // N*DTH
  float* sq    = Hx + (size_t)N * DTH;            // N
  float* HW    = sq + N;                          // N*DOUT
  float* deg   = HW + (size_t)N * DOUT;           // N
  int*   nnz_cnt = (int*)(deg + N);               // N
  int*   nnz_idx = nnz_cnt + N;                   // N*ROWCAP
  float* nnz_val = (float*)(nnz_idx + (size_t)N * ROWCAP); // N*ROWCAP

  k_bn_stats<<<DIN, 256, 0, stream>>>(H, gamma, beta, scale, shift);
  k_rows<<<N, 256, 0, stream>>>(H, scale, shift, Wt, bt, Wo, bo, Hx, sq, HW);
  k_adj<<<N, 256, 0, stream>>>(A_adj, Hx, sq, A3, deg, nnz_cnt, nnz_idx, nnz_val);
  k_out<<<N, DOUT, 0, stream>>>(HW, deg, nnz_cnt, nnz_idx, nnz_val, out);
}

// Round 2
// 609.432 us; speedup vs baseline: 1.2932x; 1.2932x over previous
//
#include <hip/hip_runtime.h>
#include <cstdint>
#include <cstddef>

#define N 8192
#define DIN 128
#define DTH 256
#define DOUT 128
#define ROWCAP 256
#define LISTCAP 1024
#define RPB 16          // rows per block in k_rows

// ---------------- threefry2x32 with key (0, 42) --------------------------
__device__ __forceinline__ void threefry_0_42(uint32_t x0, uint32_t x1,
                                              uint32_t& o0, uint32_t& o1) {
  const uint32_t ks0 = 0u;
  const uint32_t ks1 = 42u;
  const uint32_t ks2 = 0x1BD11BDAu ^ 0u ^ 42u;
  x0 += ks0; x1 += ks1;
#define TF_R(r) { x0 += x1; x1 = (x1 << (r)) | (x1 >> (32 - (r))); x1 ^= x0; }
  TF_R(13) TF_R(15) TF_R(26) TF_R(6)
  x0 += ks1; x1 += ks2 + 1u;
  TF_R(17) TF_R(29) TF_R(16) TF_R(24)
  x0 += ks2; x1 += ks0 + 2u;
  TF_R(13) TF_R(15) TF_R(26) TF_R(6)
  x0 += ks0; x1 += ks1 + 3u;
  TF_R(17) TF_R(29) TF_R(16) TF_R(24)
  x0 += ks1; x1 += ks2 + 4u;
  TF_R(13) TF_R(15) TF_R(26) TF_R(6)
  x0 += ks2; x1 += ks0 + 5u;
#undef TF_R
  o0 = x0; o1 = x1;
}

__device__ __forceinline__ bool dropedge_keep(uint32_t t) {
  uint32_t y0, y1;
  threefry_0_42(0u, t, y0, y1);
  uint32_t bits = y0 ^ y1;
  float u = __uint_as_float((bits >> 9) | 0x3f800000u) - 1.0f;
  return u < 0.8f;
}

// ---------------- K1a: BN partial sums (coalesced) -----------------------
__global__ __launch_bounds__(256) void k_bn_part(const float* __restrict__ H,
                                                 float* __restrict__ part_s,
                                                 float* __restrict__ part_s2) {
  __shared__ float ls[8][DIN];
  __shared__ float ls2[8][DIN];
  int tid = threadIdx.x;
  int rg = tid >> 5;       // 0..7
  int c4 = tid & 31;       // float4 column index
  int rbase = blockIdx.x * 128;
  float s[4] = {0,0,0,0}, s2[4] = {0,0,0,0};
  for (int k = 0; k < 16; ++k) {
    int r = rbase + rg + k * 8;
    float4 h = ((const float4*)(H + (size_t)r * DIN))[c4];
    s[0] += h.x; s2[0] += h.x * h.x;
    s[1] += h.y; s2[1] += h.y * h.y;
    s[2] += h.z; s2[2] += h.z * h.z;
    s[3] += h.w; s2[3] += h.w * h.w;
  }
#pragma unroll
  for (int q = 0; q < 4; ++q) { ls[rg][c4*4+q] = s[q]; ls2[rg][c4*4+q] = s2[q]; }
  __syncthreads();
  if (tid < DIN) {
    float a = 0.f, b = 0.f;
#pragma unroll
    for (int g = 0; g < 8; ++g) { a += ls[g][tid]; b += ls2[g][tid]; }
    part_s[blockIdx.x * DIN + tid] = a;
    part_s2[blockIdx.x * DIN + tid] = b;
  }
}

// ---------------- K1b: finalize scale/shift ------------------------------
__global__ void k_bn_final(const float* __restrict__ part_s,
                           const float* __restrict__ part_s2,
                           const float* __restrict__ gamma,
                           const float* __restrict__ beta,
                           float* __restrict__ scale,
                           float* __restrict__ shift) {
  int c = threadIdx.x;   // 128
  float s = 0.f, s2 = 0.f;
  for (int b = 0; b < 64; ++b) { s += part_s[b*DIN+c]; s2 += part_s2[b*DIN+c]; }
  float mean = s * (1.0f / N);
  float var  = s2 * (1.0f / N) - mean * mean;
  float sc = rsqrtf(var + 1e-5f) * gamma[c];
  scale[c] = sc;
  shift[c] = beta[c] - mean * sc;
}

// ---------------- K2: tiled Hn / Hx / HW ---------------------------------
__global__ __launch_bounds__(256) void k_rows(
    const float* __restrict__ H, const float* __restrict__ scale,
    const float* __restrict__ shift,
    const float* __restrict__ Wt, const float* __restrict__ bt,
    const float* __restrict__ Wo, const float* __restrict__ bo,
    float* __restrict__ Hx, float* __restrict__ HW) {
  __shared__ float hn[RPB][DIN];   // 8 KB
  __shared__ float ssc[DIN], ssh[DIN];
  int tid = threadIdx.x;
  int base = blockIdx.x * RPB;
  if (tid < DIN) { ssc[tid] = scale[tid]; ssh[tid] = shift[tid]; }
  __syncthreads();
  // stage RPB normalized rows, coalesced
#pragma unroll
  for (int k = 0; k < RPB * DIN / 4 / 256; ++k) {   // 2 iters
    int f = tid + k * 256;
    int r = f >> 5;            // / (DIN/4)
    int c4 = f & 31;
    float4 h = ((const float4*)(H + (size_t)(base + r) * DIN))[c4];
    h.x = h.x * ssc[c4*4+0] + ssh[c4*4+0];
    h.y = h.y * ssc[c4*4+1] + ssh[c4*4+1];
    h.z = h.z * ssc[c4*4+2] + ssh[c4*4+2];
    h.w = h.w * ssc[c4*4+3] + ssh[c4*4+3];
    ((float4*)hn[r])[c4] = h;
  }
  __syncthreads();
  // Hx: thread = theta-column tid (0..255)
  {
    const float4* w = (const float4*)(Wt + (size_t)tid * DIN);
    float bv = bt[tid];
    float acc[RPB];
#pragma unroll
    for (int r = 0; r < RPB; ++r) acc[r] = bv;
    for (int c4 = 0; c4 < DIN / 4; ++c4) {
      float4 wv = w[c4];
#pragma unroll
      for (int r = 0; r < RPB; ++r) {
        acc[r] += wv.x * hn[r][c4*4+0] + wv.y * hn[r][c4*4+1]
                + wv.z * hn[r][c4*4+2] + wv.w * hn[r][c4*4+3];
      }
    }
#pragma unroll
    for (int r = 0; r < RPB; ++r)
      Hx[(size_t)(base + r) * DTH + tid] = acc[r];
  }
  // HW: thread = out-column tid (0..127)
  if (tid < DOUT) {
    const float4* w = (const float4*)(Wo + (size_t)tid * DIN);
    float bv = bo[tid];
    float acc[RPB];
#pragma unroll
    for (int r = 0; r < RPB; ++r) acc[r] = bv;
    for (int c4 = 0; c4 < DIN / 4; ++c4) {
      float4 wv = w[c4];
#pragma unroll
      for (int r = 0; r < RPB; ++r) {
        acc[r] += wv.x * hn[r][c4*4+0] + wv.y * hn[r][c4*4+1]
                + wv.z * hn[r][c4*4+2] + wv.w * hn[r][c4*4+3];
      }
    }
#pragma unroll
    for (int r = 0; r < RPB; ++r)
      HW[(size_t)(base + r) * DOUT + tid] = acc[r];
  }
}

// ---------------- K2b: sq[i] = ||Hx_i||^2, one wave per row --------------
__global__ __launch_bounds__(256) void k_sq(const float* __restrict__ Hx,
                                            float* __restrict__ sq) {
  int wave = threadIdx.x >> 6;         // 0..3
  int lane = threadIdx.x & 63;
  int row = blockIdx.x * 4 + wave;
  float4 h = ((const float4*)(Hx + (size_t)row * DTH))[lane];
  float v = h.x*h.x + h.y*h.y + h.z*h.z + h.w*h.w;
#pragma unroll
  for (int off = 32; off > 0; off >>= 1) v += __shfl_xor(v, off, 64);
  if (lane == 0) sq[row] = v;
}

// ---------------- K3: N^2 stream + sparse edge work ----------------------
__global__ __launch_bounds__(256) void k_adj(
    const float* __restrict__ A_adj, const float* __restrict__ Hx,
    const float* __restrict__ sq, float* __restrict__ A3,
    float* __restrict__ deg, int* __restrict__ nnz_cnt,
    int* __restrict__ nnz_idx, float* __restrict__ nnz_val) {
  __shared__ float hx_i[DTH];
  __shared__ int   s_list[LISTCAP];
  __shared__ int   s_cnt;
  __shared__ float s_deg;
  __shared__ int   s_nnz;
  int i = blockIdx.x;
  int tid = threadIdx.x;    // 256
  if (tid == 0) { s_cnt = 0; s_deg = 0.f; s_nnz = 0; }
  if (tid < DTH) hx_i[tid] = Hx[(size_t)i * DTH + tid];
  __syncthreads();

  const size_t rowoff = (size_t)i * N;
  const float4* arow = (const float4*)(A_adj + rowoff);
  float4* a3row4 = (float4*)(A3 + rowoff);

  // phase 1a: unconditional zero-fill (independent of loads -> full MLP)
  const float4 z = make_float4(0.f, 0.f, 0.f, 0.f);
#pragma unroll
  for (int it = 0; it < 8; ++it) a3row4[tid + it * 256] = z;
  // phase 1b: prefetch all 8 quads, then compact nonzero columns
  float4 a[8];
#pragma unroll
  for (int it = 0; it < 8; ++it) a[it] = arow[tid + it * 256];
#pragma unroll
  for (int it = 0; it < 8; ++it) {
    float av[4] = {a[it].x, a[it].y, a[it].z, a[it].w};
    int j = (tid + it * 256) * 4;
#pragma unroll
    for (int q = 0; q < 4; ++q) {
      if (av[q] != 0.f) {
        int p = atomicAdd(&s_cnt, 1);
        if (p < LISTCAP) s_list[p] = j + q;
      }
    }
  }
  __syncthreads();   // also orders the zero stores before phase-2 stores

  int M = s_cnt; if (M > LISTCAP) M = LISTCAP;
  float sqi = sq[i];
  for (int t = tid; t < M; t += 256) {
    int j = s_list[t];
    uint32_t r = (uint32_t)min(i, j), c = (uint32_t)max(i, j);
    bool keep = dropedge_keep(r * (uint32_t)N + c);
    const float4* hj = (const float4*)(Hx + (size_t)j * DTH);
    float dot = 0.f;
#pragma unroll 8
    for (int c4 = 0; c4 < DTH / 4; ++c4) {
      float4 h = hj[c4];
      dot += h.x * hx_i[c4*4+0] + h.y * hx_i[c4*4+1]
           + h.z * hx_i[c4*4+2] + h.w * hx_i[c4*4+3];
    }
    float dist = sqi + sq[j] - 2.0f * dot;
    dist = sqrtf(fmaxf(dist, 1e-12f));
    float aval = expf(-0.2f * dist);
    float sg = 1.0f / (1.0f + expf(-aval));
    sg = fmaxf(sg, 0.1f);
    float b = keep ? sg : 0.0f;
    float a2 = b + ((i == j) ? 1.0f : 0.0f);
    float a3v = (a2 > 0.6f) ? a2 : 0.0f;
    A3[rowoff + j] = a3v;
    if (a3v != 0.f) {
      atomicAdd(&s_deg, a3v);
      int p = atomicAdd(&s_nnz, 1);
      if (p < ROWCAP) {
        nnz_idx[(size_t)i * ROWCAP + p] = j;
        nnz_val[(size_t)i * ROWCAP + p] = a3v;
      }
    }
  }
  __syncthreads();
  if (tid == 0) { deg[i] = s_deg; nnz_cnt[i] = min(s_nnz, ROWCAP); }
}

// ---------------- K4: out = lrelu(D^-1/2 A3 D^-1/2 @ HW) -----------------
__global__ __launch_bounds__(128) void k_out(
    const float* __restrict__ HW, const float* __restrict__ deg,
    const int* __restrict__ nnz_cnt, const int* __restrict__ nnz_idx,
    const float* __restrict__ nnz_val, float* __restrict__ out) {
  int i = blockIdx.x;
  int c = threadIdx.x;      // 128
  int cnt = nnz_cnt[i];
  float acc = 0.f;
  for (int e = 0; e < cnt; ++e) {
    int j = nnz_idx[(size_t)i * ROWCAP + e];
    float v = nnz_val[(size_t)i * ROWCAP + e];
    acc += v * rsqrtf(deg[j]) * HW[(size_t)j * DOUT + c];
  }
  float o = rsqrtf(deg[i]) * acc;
  out[(size_t)i * DOUT + c] = (o >= 0.f) ? o : 0.01f * o;
}

// ---------------- launch --------------------------------------------------
extern "C" void kernel_launch(void* const* d_in, const int* in_sizes, int n_in,
                              void* d_out, int out_size, void* d_ws, size_t ws_size,
                              hipStream_t stream) {
  const float* H     = (const float*)d_in[0];
  const float* A_adj = (const float*)d_in[1];
  const float* gamma = (const float*)d_in[2];
  const float* beta  = (const float*)d_in[3];
  const float* Wt    = (const float*)d_in[4];
  const float* bt    = (const float*)d_in[5];
  const float* Wo    = (const float*)d_in[6];
  const float* bo    = (const float*)d_in[7];

  float* out = (float*)d_out;                    // [N, DOUT]
  float* A3  = out + (size_t)N * DOUT;           // [N, N]

  float* ws    = (float*)d_ws;
  float* scale = ws;                              // 128
  float* shift = ws + 128;                        // 128
  float* Hx    = ws + 256;                        // N*DTH
  float* sq    = Hx + (size_t)N * DTH;            // N
  float* HW    = sq + N;                          // N*DOUT
  float* deg   = HW + (size_t)N * DOUT;           // N
  int*   nnz_cnt = (int*)(deg + N);               // N
  int*   nnz_idx = nnz_cnt + N;                   // N*ROWCAP
  float* nnz_val = (float*)(nnz_idx + (size_t)N * ROWCAP); // N*ROWCAP
  float* part_s  = nnz_val + (size_t)N * ROWCAP;  // 64*128
  float* part_s2 = part_s + 64 * DIN;             // 64*128

  k_bn_part<<<64, 256, 0, stream>>>(H, part_s, part_s2);
  k_bn_final<<<1, DIN, 0, stream>>>(part_s, part_s2, gamma, beta, scale, shift);
  k_rows<<<N / RPB, 256, 0, stream>>>(H, scale, shift, Wt, bt, Wo, bo, Hx, HW);
  k_sq<<<N / 4, 256, 0, stream>>>(Hx, sq);
  k_adj<<<N, 256, 0, stream>>>(A_adj, Hx, sq, A3, deg, nnz_cnt, nnz_idx, nnz_val);
  k_out<<<N, DOUT, 0, stream>>>(HW, deg, nnz_cnt, nnz_idx, nnz_val, out);
}

// Round 3
// 546.673 us; speedup vs baseline: 1.4417x; 1.1148x over previous
//
#include <hip/hip_runtime.h>
#include <cstdint>
#include <cstddef>

#define N 8192
#define DIN 128
#define DTH 256
#define DOUT 128
#define ROWCAP 256
#define LISTCAP 512

// ---------------- threefry2x32 with key (0, 42) --------------------------
__device__ __forceinline__ void threefry_0_42(uint32_t x0, uint32_t x1,
                                              uint32_t& o0, uint32_t& o1) {
  const uint32_t ks0 = 0u;
  const uint32_t ks1 = 42u;
  const uint32_t ks2 = 0x1BD11BDAu ^ 0u ^ 42u;
  x0 += ks0; x1 += ks1;
#define TF_R(r) { x0 += x1; x1 = (x1 << (r)) | (x1 >> (32 - (r))); x1 ^= x0; }
  TF_R(13) TF_R(15) TF_R(26) TF_R(6)
  x0 += ks1; x1 += ks2 + 1u;
  TF_R(17) TF_R(29) TF_R(16) TF_R(24)
  x0 += ks2; x1 += ks0 + 2u;
  TF_R(13) TF_R(15) TF_R(26) TF_R(6)
  x0 += ks0; x1 += ks1 + 3u;
  TF_R(17) TF_R(29) TF_R(16) TF_R(24)
  x0 += ks1; x1 += ks2 + 4u;
  TF_R(13) TF_R(15) TF_R(26) TF_R(6)
  x0 += ks2; x1 += ks0 + 5u;
#undef TF_R
  o0 = x0; o1 = x1;
}

__device__ __forceinline__ bool dropedge_keep(uint32_t t) {
  uint32_t y0, y1;
  threefry_0_42(0u, t, y0, y1);
  uint32_t bits = y0 ^ y1;
  float u = __uint_as_float((bits >> 9) | 0x3f800000u) - 1.0f;
  return u < 0.8f;
}

// ---------------- K0: pure write-stream zero of A3 -----------------------
__global__ __launch_bounds__(256) void k_zero(float4* __restrict__ A3) {
  size_t idx = (size_t)blockIdx.x * 256 + threadIdx.x;
  const float4 z = make_float4(0.f, 0.f, 0.f, 0.f);
#pragma unroll
  for (int it = 0; it < 8; ++it)
    A3[idx + (size_t)it * 8192 * 256] = z;   // 16M float4 total
}

// ---------------- K1a: BN partial sums (coalesced) -----------------------
__global__ __launch_bounds__(256) void k_bn_part(const float* __restrict__ H,
                                                 float* __restrict__ part_s,
                                                 float* __restrict__ part_s2) {
  __shared__ float ls[8][DIN];
  __shared__ float ls2[8][DIN];
  int tid = threadIdx.x;
  int rg = tid >> 5;
  int c4 = tid & 31;
  int rbase = blockIdx.x * 128;
  float s[4] = {0,0,0,0}, s2[4] = {0,0,0,0};
  for (int k = 0; k < 16; ++k) {
    int r = rbase + rg + k * 8;
    float4 h = ((const float4*)(H + (size_t)r * DIN))[c4];
    s[0] += h.x; s2[0] += h.x * h.x;
    s[1] += h.y; s2[1] += h.y * h.y;
    s[2] += h.z; s2[2] += h.z * h.z;
    s[3] += h.w; s2[3] += h.w * h.w;
  }
#pragma unroll
  for (int q = 0; q < 4; ++q) { ls[rg][c4*4+q] = s[q]; ls2[rg][c4*4+q] = s2[q]; }
  __syncthreads();
  if (tid < DIN) {
    float a = 0.f, b = 0.f;
#pragma unroll
    for (int g = 0; g < 8; ++g) { a += ls[g][tid]; b += ls2[g][tid]; }
    part_s[blockIdx.x * DIN + tid] = a;
    part_s2[blockIdx.x * DIN + tid] = b;
  }
}

// ---------------- K1b: finalize scale/shift ------------------------------
__global__ void k_bn_final(const float* __restrict__ part_s,
                           const float* __restrict__ part_s2,
                           const float* __restrict__ gamma,
                           const float* __restrict__ beta,
                           float* __restrict__ scale,
                           float* __restrict__ shift) {
  int c = threadIdx.x;   // 128
  float s = 0.f, s2 = 0.f;
  for (int b = 0; b < 64; ++b) { s += part_s[b*DIN+c]; s2 += part_s2[b*DIN+c]; }
  float mean = s * (1.0f / N);
  float var  = s2 * (1.0f / N) - mean * mean;
  float sc = rsqrtf(var + 1e-5f) * gamma[c];
  scale[c] = sc;
  shift[c] = beta[c] - mean * sc;
}

// ---------------- K1c: pack W into k-major Wc[128][384] + bias bc[384] ---
__global__ void k_prep(const float* __restrict__ Wt, const float* __restrict__ bt,
                       const float* __restrict__ Wo, const float* __restrict__ bo,
                       float* __restrict__ Wc, float* __restrict__ bc) {
  int idx = blockIdx.x * 256 + threadIdx.x;
  if (blockIdx.x < 192) {            // 192*256 = 49152 = 128*384
    int k = idx / 384, c = idx % 384;
    Wc[idx] = (c < 256) ? Wt[(size_t)c * DIN + k] : Wo[(size_t)(c - 256) * DIN + k];
  } else {
    int c = idx - 192 * 256;
    if (c < 384) bc[c] = (c < 256) ? bt[c] : bo[c - 256];
  }
}

// ---------------- K2: Hx / HW / sq, register-tiled -----------------------
// block = 256 thr = 4 waves; block covers 16 rows (4 per wave); lane c
// computes cols {c+64q}, q=0..3 -> Hx, q=4..5 -> HW.
__global__ __launch_bounds__(256) void k_rows(
    const float* __restrict__ H, const float* __restrict__ scale,
    const float* __restrict__ shift, const float* __restrict__ Wc,
    const float* __restrict__ bc, float* __restrict__ Hx,
    float* __restrict__ HW, float* __restrict__ sq) {
  __shared__ float hn[16][DIN];   // 8 KB; all reads below are wave-broadcast
  int tid = threadIdx.x;
  int base = blockIdx.x * 16;
#pragma unroll
  for (int k = 0; k < 2; ++k) {
    int f = tid + k * 256;
    int r = f >> 5, c4 = f & 31;
    float4 h  = ((const float4*)(H + (size_t)(base + r) * DIN))[c4];
    float4 sc = ((const float4*)scale)[c4];
    float4 sh = ((const float4*)shift)[c4];
    h.x = h.x * sc.x + sh.x; h.y = h.y * sc.y + sh.y;
    h.z = h.z * sc.z + sh.z; h.w = h.w * sc.w + sh.w;
    ((float4*)hn[r])[c4] = h;
  }
  __syncthreads();
  int w = tid >> 6, lane = tid & 63;
  int r0 = w * 4;
  float acc[4][6];
#pragma unroll
  for (int r = 0; r < 4; ++r)
#pragma unroll
    for (int q = 0; q < 6; ++q) acc[r][q] = 0.f;

  for (int k4 = 0; k4 < 32; ++k4) {
    float4 h[4];
#pragma unroll
    for (int r = 0; r < 4; ++r) h[r] = ((const float4*)hn[r0 + r])[k4];  // ds_read_b128 broadcast
#pragma unroll
    for (int kk = 0; kk < 4; ++kk) {
      const float* wrow = Wc + (size_t)(k4 * 4 + kk) * 384 + lane;
      float wv[6];
#pragma unroll
      for (int q = 0; q < 6; ++q) wv[q] = wrow[64 * q];   // coalesced dword loads
#pragma unroll
      for (int r = 0; r < 4; ++r) {
        float hs = (kk == 0) ? h[r].x : (kk == 1) ? h[r].y
                 : (kk == 2) ? h[r].z : h[r].w;
#pragma unroll
        for (int q = 0; q < 6; ++q) acc[r][q] += hs * wv[q];
      }
    }
  }
#pragma unroll
  for (int r = 0; r < 4; ++r) {
    int row = base + r0 + r;
    float s = 0.f;
#pragma unroll
    for (int q = 0; q < 4; ++q) {
      float v = acc[r][q] + bc[lane + 64 * q];
      Hx[(size_t)row * DTH + lane + 64 * q] = v;
      s += v * v;
    }
#pragma unroll
    for (int off = 32; off > 0; off >>= 1) s += __shfl_xor(s, off, 64);
    if (lane == 0) sq[row] = s;
#pragma unroll
    for (int q = 4; q < 6; ++q) {
      float v = acc[r][q] + bc[lane + 64 * q];
      HW[(size_t)row * DOUT + lane + 64 * (q - 4)] = v;
    }
  }
}

// ---------------- K3: read-stream A_adj, compact, per-edge values --------
__global__ __launch_bounds__(256) void k_edges(
    const float* __restrict__ A_adj, const float* __restrict__ Hx,
    const float* __restrict__ sq,
    float* __restrict__ deg, int* __restrict__ nnz_cnt,
    int* __restrict__ nnz_idx, float* __restrict__ nnz_val) {
  __shared__ float hx_i[DTH];
  __shared__ int   s_list[LISTCAP];
  __shared__ int   s_cnt;
  __shared__ float s_deg;
  __shared__ int   s_nnz;
  int i = blockIdx.x;
  int tid = threadIdx.x;    // 256
  if (tid == 0) { s_cnt = 0; s_deg = 0.f; s_nnz = 0; }
  hx_i[tid] = Hx[(size_t)i * DTH + tid];
  __syncthreads();

  const float4* arow = (const float4*)(A_adj + (size_t)i * N);
  float4 a[8];
#pragma unroll
  for (int it = 0; it < 8; ++it) a[it] = arow[tid + it * 256];
#pragma unroll
  for (int it = 0; it < 8; ++it) {
    float av[4] = {a[it].x, a[it].y, a[it].z, a[it].w};
    int j = (tid + it * 256) * 4;
#pragma unroll
    for (int q = 0; q < 4; ++q) {
      if (av[q] != 0.f) {
        int p = atomicAdd(&s_cnt, 1);
        if (p < LISTCAP) s_list[p] = j + q;
      }
    }
  }
  __syncthreads();

  int M = min(s_cnt, LISTCAP);
  float sqi = sq[i];
  for (int t = tid; t < M; t += 256) {
    int j = s_list[t];
    uint32_t r = (uint32_t)min(i, j), c = (uint32_t)max(i, j);
    bool keep = dropedge_keep(r * (uint32_t)N + c);
    const float4* hj = (const float4*)(Hx + (size_t)j * DTH);
    float dot = 0.f;
#pragma unroll 8
    for (int c4 = 0; c4 < DTH / 4; ++c4) {
      float4 h = hj[c4];
      dot += h.x * hx_i[c4*4+0] + h.y * hx_i[c4*4+1]
           + h.z * hx_i[c4*4+2] + h.w * hx_i[c4*4+3];
    }
    float dist = sqi + sq[j] - 2.0f * dot;
    dist = sqrtf(fmaxf(dist, 1e-12f));
    float aval = expf(-0.2f * dist);
    float sg = 1.0f / (1.0f + expf(-aval));
    sg = fmaxf(sg, 0.1f);
    float b = keep ? sg : 0.0f;
    float a2 = b + ((i == j) ? 1.0f : 0.0f);
    float a3v = (a2 > 0.6f) ? a2 : 0.0f;
    if (a3v != 0.f) {
      atomicAdd(&s_deg, a3v);
      int p = atomicAdd(&s_nnz, 1);
      if (p < ROWCAP) {
        nnz_idx[(size_t)i * ROWCAP + p] = j;
        nnz_val[(size_t)i * ROWCAP + p] = a3v;
      }
    }
  }
  __syncthreads();
  if (tid == 0) { deg[i] = s_deg; nnz_cnt[i] = min(s_nnz, ROWCAP); }
}

// ---------------- K3b: scatter surviving values into A3 ------------------
__global__ __launch_bounds__(256) void k_scatter(
    const int* __restrict__ nnz_cnt, const int* __restrict__ nnz_idx,
    const float* __restrict__ nnz_val, float* __restrict__ A3) {
  int i = blockIdx.x * 256 + threadIdx.x;   // one thread per row
  if (i >= N) return;
  int cnt = nnz_cnt[i];
  for (int e = 0; e < cnt; ++e)
    A3[(size_t)i * N + nnz_idx[(size_t)i * ROWCAP + e]] =
        nnz_val[(size_t)i * ROWCAP + e];
}

// ---------------- K4: out = lrelu(D^-1/2 A3 D^-1/2 @ HW) -----------------
__global__ __launch_bounds__(128) void k_out(
    const float* __restrict__ HW, const float* __restrict__ deg,
    const int* __restrict__ nnz_cnt, const int* __restrict__ nnz_idx,
    const float* __restrict__ nnz_val, float* __restrict__ out) {
  int i = blockIdx.x;
  int c = threadIdx.x;      // 128
  int cnt = nnz_cnt[i];
  float acc = 0.f;
  for (int e = 0; e < cnt; ++e) {
    int j = nnz_idx[(size_t)i * ROWCAP + e];
    float v = nnz_val[(size_t)i * ROWCAP + e];
    acc += v * rsqrtf(deg[j]) * HW[(size_t)j * DOUT + c];
  }
  float o = rsqrtf(deg[i]) * acc;
  out[(size_t)i * DOUT + c] = (o >= 0.f) ? o : 0.01f * o;
}

// ---------------- launch --------------------------------------------------
extern "C" void kernel_launch(void* const* d_in, const int* in_sizes, int n_in,
                              void* d_out, int out_size, void* d_ws, size_t ws_size,
                              hipStream_t stream) {
  const float* H     = (const float*)d_in[0];
  const float* A_adj = (const float*)d_in[1];
  const float* gamma = (const float*)d_in[2];
  const float* beta  = (const float*)d_in[3];
  const float* Wt    = (const float*)d_in[4];
  const float* bt    = (const float*)d_in[5];
  const float* Wo    = (const float*)d_in[6];
  const float* bo    = (const float*)d_in[7];

  float* out = (float*)d_out;                    // [N, DOUT]
  float* A3  = out + (size_t)N * DOUT;           // [N, N]

  float* ws    = (float*)d_ws;
  float* scale = ws;                              // 128
  float* shift = ws + 128;                        // 128
  float* Hx    = ws + 256;                        // N*DTH
  float* sq    = Hx + (size_t)N * DTH;            // N
  float* HW    = sq + N;                          // N*DOUT
  float* deg   = HW + (size_t)N * DOUT;           // N
  int*   nnz_cnt = (int*)(deg + N);               // N
  int*   nnz_idx = nnz_cnt + N;                   // N*ROWCAP
  float* nnz_val = (float*)(nnz_idx + (size_t)N * ROWCAP); // N*ROWCAP
  float* part_s  = nnz_val + (size_t)N * ROWCAP;  // 64*128
  float* part_s2 = part_s + 64 * DIN;             // 64*128
  float* Wc      = part_s2 + 64 * DIN;            // 128*384
  float* bc      = Wc + 128 * 384;                // 384

  k_zero<<<8192, 256, 0, stream>>>((float4*)A3);
  k_bn_part<<<64, 256, 0, stream>>>(H, part_s, part_s2);
  k_bn_final<<<1, DIN, 0, stream>>>(part_s, part_s2, gamma, beta, scale, shift);
  k_prep<<<194, 256, 0, stream>>>(Wt, bt, Wo, bo, Wc, bc);
  k_rows<<<N / 16, 256, 0, stream>>>(H, scale, shift, Wc, bc, Hx, HW, sq);
  k_edges<<<N, 256, 0, stream>>>(A_adj, Hx, sq, deg, nnz_cnt, nnz_idx, nnz_val);
  k_scatter<<<32, 256, 0, stream>>>(nnz_cnt, nnz_idx, nnz_val, A3);
  k_out<<<N, DOUT, 0, stream>>>(HW, deg, nnz_cnt, nnz_idx, nnz_val, out);
}

// Round 4
// 492.109 us; speedup vs baseline: 1.6015x; 1.1109x over previous
//
#include <hip/hip_runtime.h>
#include <cstdint>
#include <cstddef>

#define N 8192
#define DIN 128
#define DTH 256
#define DOUT 128
#define ROWCAP 256
#define LISTCAP 512

// ---------------- threefry2x32 with key (0, 42) --------------------------
__device__ __forceinline__ void threefry_0_42(uint32_t x0, uint32_t x1,
                                              uint32_t& o0, uint32_t& o1) {
  const uint32_t ks0 = 0u;
  const uint32_t ks1 = 42u;
  const uint32_t ks2 = 0x1BD11BDAu ^ 0u ^ 42u;
  x0 += ks0; x1 += ks1;
#define TF_R(r) { x0 += x1; x1 = (x1 << (r)) | (x1 >> (32 - (r))); x1 ^= x0; }
  TF_R(13) TF_R(15) TF_R(26) TF_R(6)
  x0 += ks1; x1 += ks2 + 1u;
  TF_R(17) TF_R(29) TF_R(16) TF_R(24)
  x0 += ks2; x1 += ks0 + 2u;
  TF_R(13) TF_R(15) TF_R(26) TF_R(6)
  x0 += ks0; x1 += ks1 + 3u;
  TF_R(17) TF_R(29) TF_R(16) TF_R(24)
  x0 += ks1; x1 += ks2 + 4u;
  TF_R(13) TF_R(15) TF_R(26) TF_R(6)
  x0 += ks2; x1 += ks0 + 5u;
#undef TF_R
  o0 = x0; o1 = x1;
}

__device__ __forceinline__ bool dropedge_keep(uint32_t t) {
  uint32_t y0, y1;
  threefry_0_42(0u, t, y0, y1);
  uint32_t bits = y0 ^ y1;
  float u = __uint_as_float((bits >> 9) | 0x3f800000u) - 1.0f;
  return u < 0.8f;
}

// ---------------- K1: fused bn_part + W pack + counter zero --------------
// blocks [0,64): BN partial sums; [64,256): Wc pack; [256,258): bc;
// [258,274): zero deg + nnz_cnt (contiguous 64 KB).
__global__ __launch_bounds__(256) void k_pre(
    const float* __restrict__ H,
    const float* __restrict__ Wt, const float* __restrict__ bt,
    const float* __restrict__ Wo, const float* __restrict__ bo,
    float* __restrict__ part_s, float* __restrict__ part_s2,
    float* __restrict__ Wc, float* __restrict__ bc,
    float* __restrict__ deg /* deg + nnz_cnt contiguous */) {
  int b = blockIdx.x;
  int tid = threadIdx.x;
  if (b < 64) {
    __shared__ float ls[8][DIN];
    __shared__ float ls2[8][DIN];
    int rg = tid >> 5;
    int c4 = tid & 31;
    int rbase = b * 128;
    float s[4] = {0,0,0,0}, s2[4] = {0,0,0,0};
    for (int k = 0; k < 16; ++k) {
      int r = rbase + rg + k * 8;
      float4 h = ((const float4*)(H + (size_t)r * DIN))[c4];
      s[0] += h.x; s2[0] += h.x * h.x;
      s[1] += h.y; s2[1] += h.y * h.y;
      s[2] += h.z; s2[2] += h.z * h.z;
      s[3] += h.w; s2[3] += h.w * h.w;
    }
#pragma unroll
    for (int q = 0; q < 4; ++q) { ls[rg][c4*4+q] = s[q]; ls2[rg][c4*4+q] = s2[q]; }
    __syncthreads();
    if (tid < DIN) {
      float a = 0.f, bb = 0.f;
#pragma unroll
      for (int g = 0; g < 8; ++g) { a += ls[g][tid]; bb += ls2[g][tid]; }
      part_s[b * DIN + tid] = a;
      part_s2[b * DIN + tid] = bb;
    }
  } else if (b < 256) {
    int idx = (b - 64) * 256 + tid;        // [0, 49152)
    int k = idx / 384, c = idx % 384;
    Wc[idx] = (c < 256) ? Wt[(size_t)c * DIN + k] : Wo[(size_t)(c - 256) * DIN + k];
  } else if (b < 258) {
    int c = (b - 256) * 256 + tid;
    if (c < 384) bc[c] = (c < 256) ? bt[c] : bo[c - 256];
  } else {
    int g = (b - 258) * 256 + tid;         // [0, 4096) int4 = 64 KB
    ((int4*)deg)[g] = make_int4(0, 0, 0, 0);
  }
}

// ---------------- K2: finalize scale/shift -------------------------------
__global__ void k_bn_final(const float* __restrict__ part_s,
                           const float* __restrict__ part_s2,
                           const float* __restrict__ gamma,
                           const float* __restrict__ beta,
                           float* __restrict__ scale,
                           float* __restrict__ shift) {
  int c = threadIdx.x;   // 128
  float s = 0.f, s2 = 0.f;
  for (int b = 0; b < 64; ++b) { s += part_s[b*DIN+c]; s2 += part_s2[b*DIN+c]; }
  float mean = s * (1.0f / N);
  float var  = s2 * (1.0f / N) - mean * mean;
  float sc = rsqrtf(var + 1e-5f) * gamma[c];
  scale[c] = sc;
  shift[c] = beta[c] - mean * sc;
}

__device__ __forceinline__ unsigned short f2bf(float v) {
  uint32_t u = __float_as_uint(v);
  u += 0x7fffu + ((u >> 16) & 1u);     // round-to-nearest-even
  return (unsigned short)(u >> 16);
}

// ---------------- K3: Hxh(bf16) / HW / sq, register-tiled ----------------
__global__ __launch_bounds__(256) void k_rows(
    const float* __restrict__ H, const float* __restrict__ scale,
    const float* __restrict__ shift, const float* __restrict__ Wc,
    const float* __restrict__ bc, unsigned short* __restrict__ Hxh,
    float* __restrict__ HW, float* __restrict__ sq) {
  __shared__ float hn[16][DIN];   // 8 KB; reads below are wave-broadcast
  int tid = threadIdx.x;
  int base = blockIdx.x * 16;
#pragma unroll
  for (int k = 0; k < 2; ++k) {
    int f = tid + k * 256;
    int r = f >> 5, c4 = f & 31;
    float4 h  = ((const float4*)(H + (size_t)(base + r) * DIN))[c4];
    float4 sc = ((const float4*)scale)[c4];
    float4 sh = ((const float4*)shift)[c4];
    h.x = h.x * sc.x + sh.x; h.y = h.y * sc.y + sh.y;
    h.z = h.z * sc.z + sh.z; h.w = h.w * sc.w + sh.w;
    ((float4*)hn[r])[c4] = h;
  }
  __syncthreads();
  int w = tid >> 6, lane = tid & 63;
  int r0 = w * 4;
  float acc[4][6];
#pragma unroll
  for (int r = 0; r < 4; ++r)
#pragma unroll
    for (int q = 0; q < 6; ++q) acc[r][q] = 0.f;

  for (int k4 = 0; k4 < 32; ++k4) {
    float4 h[4];
#pragma unroll
    for (int r = 0; r < 4; ++r) h[r] = ((const float4*)hn[r0 + r])[k4];
#pragma unroll
    for (int kk = 0; kk < 4; ++kk) {
      const float* wrow = Wc + (size_t)(k4 * 4 + kk) * 384 + lane;
      float wv[6];
#pragma unroll
      for (int q = 0; q < 6; ++q) wv[q] = wrow[64 * q];
#pragma unroll
      for (int r = 0; r < 4; ++r) {
        float hs = (kk == 0) ? h[r].x : (kk == 1) ? h[r].y
                 : (kk == 2) ? h[r].z : h[r].w;
#pragma unroll
        for (int q = 0; q < 6; ++q) acc[r][q] += hs * wv[q];
      }
    }
  }
#pragma unroll
  for (int r = 0; r < 4; ++r) {
    int row = base + r0 + r;
    float s = 0.f;
#pragma unroll
    for (int q = 0; q < 4; ++q) {
      float v = acc[r][q] + bc[lane + 64 * q];
      Hxh[(size_t)row * DTH + lane + 64 * q] = f2bf(v);
      s += v * v;
    }
#pragma unroll
    for (int off = 32; off > 0; off >>= 1) s += __shfl_xor(s, off, 64);
    if (lane == 0) sq[row] = s;
#pragma unroll
    for (int q = 4; q < 6; ++q) {
      float v = acc[r][q] + bc[lane + 64 * q];
      HW[(size_t)row * DOUT + lane + 64 * (q - 4)] = v;
    }
  }
}

// ---------------- K4: fused A3-zero + upper-tri edge pass ----------------
// blocks [0,8192): zero A3 row b (pure write stream)
// blocks [8192,16384): row i = b-8192, scan A_adj[i][j>=i], mirror results
__global__ __launch_bounds__(256) void k_main(
    const float* __restrict__ A_adj, const unsigned short* __restrict__ Hxh,
    const float* __restrict__ sq, float* __restrict__ A3,
    float* __restrict__ deg, int* __restrict__ nnz_cnt,
    int* __restrict__ nnz_idx, float* __restrict__ nnz_val) {
  int b = blockIdx.x;
  int tid = threadIdx.x;
  if (b < 8192) {
    float4* row = (float4*)(A3 + (size_t)b * N);
    const float4 z = make_float4(0.f, 0.f, 0.f, 0.f);
#pragma unroll
    for (int it = 0; it < 8; ++it) row[tid + it * 256] = z;
    return;
  }
  int i = b - 8192;
  __shared__ float4 hx4[64];          // hx_i as 64 float4
  __shared__ int   s_list[LISTCAP];
  __shared__ int   s_cnt;
  if (tid == 0) s_cnt = 0;
  ((float*)hx4)[tid] = __uint_as_float(((uint32_t)Hxh[(size_t)i * DTH + tid]) << 16);
  __syncthreads();

  const float4* arow = (const float4*)(A_adj + (size_t)i * N);
  int q0 = i >> 2;
  for (int q4 = q0 + tid; q4 < N / 4; q4 += 256) {
    float4 a = arow[q4];
    int jb = q4 * 4;
    float av[4] = {a.x, a.y, a.z, a.w};
#pragma unroll
    for (int q = 0; q < 4; ++q) {
      int j = jb + q;
      if (av[q] != 0.f && j >= i) {
        int p = atomicAdd(&s_cnt, 1);
        if (p < LISTCAP) s_list[p] = j;
      }
    }
  }
  __syncthreads();

  int M = min(s_cnt, LISTCAP);
  float sqi = sq[i];
  for (int t = tid; t < M; t += 256) {
    int j = s_list[t];
    bool keep = dropedge_keep((uint32_t)i * (uint32_t)N + (uint32_t)j);
    float dist;
    if (j == i) {
      dist = 1e-6f;                      // exact diagonal: clip(0,1e-12)^0.5
    } else {
      const uint4* hj = (const uint4*)(Hxh + (size_t)j * DTH);
      float dot = 0.f;
#pragma unroll 8
      for (int c = 0; c < 32; ++c) {
        uint4 u = hj[c];
        float4 f0 = hx4[2 * c], f1 = hx4[2 * c + 1];
        dot += __uint_as_float(u.x << 16) * f0.x
             + __uint_as_float(u.x & 0xffff0000u) * f0.y
             + __uint_as_float(u.y << 16) * f0.z
             + __uint_as_float(u.y & 0xffff0000u) * f0.w
             + __uint_as_float(u.z << 16) * f1.x
             + __uint_as_float(u.z & 0xffff0000u) * f1.y
             + __uint_as_float(u.w << 16) * f1.z
             + __uint_as_float(u.w & 0xffff0000u) * f1.w;
      }
      dist = sqrtf(fmaxf(sqi + sq[j] - 2.0f * dot, 1e-12f));
    }
    float aval = expf(-0.2f * dist);
    float sg = fmaxf(1.0f / (1.0f + expf(-aval)), 0.1f);
    float bb = keep ? sg : 0.0f;
    float a2 = bb + ((i == j) ? 1.0f : 0.0f);
    float a3v = (a2 > 0.6f) ? a2 : 0.0f;
    if (a3v != 0.f) {
      atomicAdd(&deg[i], a3v);
      int p = atomicAdd(&nnz_cnt[i], 1);
      if (p < ROWCAP) {
        nnz_idx[(size_t)i * ROWCAP + p] = j;
        nnz_val[(size_t)i * ROWCAP + p] = a3v;
      }
      if (j != i) {
        atomicAdd(&deg[j], a3v);
        int p2 = atomicAdd(&nnz_cnt[j], 1);
        if (p2 < ROWCAP) {
          nnz_idx[(size_t)j * ROWCAP + p2] = i;
          nnz_val[(size_t)j * ROWCAP + p2] = a3v;
        }
      }
    }
  }
}

// ---------------- K5: scatter A3 + out = lrelu(A_hat @ HW) ---------------
__global__ __launch_bounds__(128) void k_post(
    const float* __restrict__ HW, const float* __restrict__ deg,
    const int* __restrict__ nnz_cnt, const int* __restrict__ nnz_idx,
    const float* __restrict__ nnz_val, float* __restrict__ A3,
    float* __restrict__ out) {
  int i = blockIdx.x;
  int c = threadIdx.x;      // 128
  int cnt = min(nnz_cnt[i], ROWCAP);
  for (int e = c; e < cnt; e += 128)
    A3[(size_t)i * N + nnz_idx[(size_t)i * ROWCAP + e]] =
        nnz_val[(size_t)i * ROWCAP + e];
  float acc = 0.f;
  for (int e = 0; e < cnt; ++e) {
    int j = nnz_idx[(size_t)i * ROWCAP + e];
    float v = nnz_val[(size_t)i * ROWCAP + e];
    acc += v * rsqrtf(deg[j]) * HW[(size_t)j * DOUT + c];
  }
  float o = rsqrtf(deg[i]) * acc;
  out[(size_t)i * DOUT + c] = (o >= 0.f) ? o : 0.01f * o;
}

// ---------------- launch --------------------------------------------------
extern "C" void kernel_launch(void* const* d_in, const int* in_sizes, int n_in,
                              void* d_out, int out_size, void* d_ws, size_t ws_size,
                              hipStream_t stream) {
  const float* H     = (const float*)d_in[0];
  const float* A_adj = (const float*)d_in[1];
  const float* gamma = (const float*)d_in[2];
  const float* beta  = (const float*)d_in[3];
  const float* Wt    = (const float*)d_in[4];
  const float* bt    = (const float*)d_in[5];
  const float* Wo    = (const float*)d_in[6];
  const float* bo    = (const float*)d_in[7];

  float* out = (float*)d_out;                    // [N, DOUT]
  float* A3  = out + (size_t)N * DOUT;           // [N, N]

  float* ws    = (float*)d_ws;
  float* scale = ws;                              // 128
  float* shift = ws + 128;                        // 128
  unsigned short* Hxh = (unsigned short*)(ws + 256);  // N*256 bf16 (= N*128 floats)
  float* sq    = ws + 256 + (size_t)N * 128;      // N
  float* HW    = sq + N;                          // N*128
  float* deg   = HW + (size_t)N * DOUT;           // N   (deg+cnt contiguous!)
  int*   nnz_cnt = (int*)(deg + N);               // N
  int*   nnz_idx = nnz_cnt + N;                   // N*ROWCAP
  float* nnz_val = (float*)(nnz_idx + (size_t)N * ROWCAP); // N*ROWCAP
  float* part_s  = nnz_val + (size_t)N * ROWCAP;  // 64*128
  float* part_s2 = part_s + 64 * DIN;             // 64*128
  float* Wc      = part_s2 + 64 * DIN;            // 128*384
  float* bc      = Wc + 128 * 384;                // 384

  k_pre<<<274, 256, 0, stream>>>(H, Wt, bt, Wo, bo, part_s, part_s2, Wc, bc, deg);
  k_bn_final<<<1, DIN, 0, stream>>>(part_s, part_s2, gamma, beta, scale, shift);
  k_rows<<<N / 16, 256, 0, stream>>>(H, scale, shift, Wc, bc, Hxh, HW, sq);
  k_main<<<2 * N, 256, 0, stream>>>(A_adj, Hxh, sq, A3, deg, nnz_cnt, nnz_idx, nnz_val);
  k_post<<<N, DOUT, 0, stream>>>(HW, deg, nnz_cnt, nnz_idx, nnz_val, A3, out);
}

// Round 6
// 460.244 us; speedup vs baseline: 1.7124x; 1.0692x over previous
//
#include <hip/hip_runtime.h>
#include <cstdint>
#include <cstddef>

#define N 8192
#define DIN 128
#define DTH 256
#define DOUT 128
#define ROWCAP 256
#define LISTCAP 256

typedef float vfloat4 __attribute__((ext_vector_type(4)));

// ---------------- threefry2x32 with key (0, 42) --------------------------
__device__ __forceinline__ void threefry_0_42(uint32_t x0, uint32_t x1,
                                              uint32_t& o0, uint32_t& o1) {
  const uint32_t ks0 = 0u;
  const uint32_t ks1 = 42u;
  const uint32_t ks2 = 0x1BD11BDAu ^ 0u ^ 42u;
  x0 += ks0; x1 += ks1;
#define TF_R(r) { x0 += x1; x1 = (x1 << (r)) | (x1 >> (32 - (r))); x1 ^= x0; }
  TF_R(13) TF_R(15) TF_R(26) TF_R(6)
  x0 += ks1; x1 += ks2 + 1u;
  TF_R(17) TF_R(29) TF_R(16) TF_R(24)
  x0 += ks2; x1 += ks0 + 2u;
  TF_R(13) TF_R(15) TF_R(26) TF_R(6)
  x0 += ks0; x1 += ks1 + 3u;
  TF_R(17) TF_R(29) TF_R(16) TF_R(24)
  x0 += ks1; x1 += ks2 + 4u;
  TF_R(13) TF_R(15) TF_R(26) TF_R(6)
  x0 += ks2; x1 += ks0 + 5u;
#undef TF_R
  o0 = x0; o1 = x1;
}

__device__ __forceinline__ bool dropedge_keep(uint32_t t) {
  uint32_t y0, y1;
  threefry_0_42(0u, t, y0, y1);
  uint32_t bits = y0 ^ y1;
  float u = __uint_as_float((bits >> 9) | 0x3f800000u) - 1.0f;
  return u < 0.8f;
}

__device__ __forceinline__ unsigned short f2bf(float v) {
  uint32_t u = __float_as_uint(v);
  u += 0x7fffu + ((u >> 16) & 1u);     // round-to-nearest-even
  return (unsigned short)(u >> 16);
}

// ---------------- K1: fused bn_part + W pack + counter zero --------------
// blocks [0,64): BN partial sums; [64,256): Wc pack; [256,258): bc;
// [258,274): zero deg + nnz_cnt (contiguous 64 KB).
__global__ __launch_bounds__(256) void k_pre(
    const float* __restrict__ H,
    const float* __restrict__ Wt, const float* __restrict__ bt,
    const float* __restrict__ Wo, const float* __restrict__ bo,
    float* __restrict__ part_s, float* __restrict__ part_s2,
    float* __restrict__ Wc, float* __restrict__ bc,
    float* __restrict__ deg /* deg + nnz_cnt contiguous */) {
  int b = blockIdx.x;
  int tid = threadIdx.x;
  if (b < 64) {
    __shared__ float ls[8][DIN];
    __shared__ float ls2[8][DIN];
    int rg = tid >> 5;
    int c4 = tid & 31;
    int rbase = b * 128;
    float s[4] = {0,0,0,0}, s2[4] = {0,0,0,0};
    for (int k = 0; k < 16; ++k) {
      int r = rbase + rg + k * 8;
      float4 h = ((const float4*)(H + (size_t)r * DIN))[c4];
      s[0] += h.x; s2[0] += h.x * h.x;
      s[1] += h.y; s2[1] += h.y * h.y;
      s[2] += h.z; s2[2] += h.z * h.z;
      s[3] += h.w; s2[3] += h.w * h.w;
    }
#pragma unroll
    for (int q = 0; q < 4; ++q) { ls[rg][c4*4+q] = s[q]; ls2[rg][c4*4+q] = s2[q]; }
    __syncthreads();
    if (tid < DIN) {
      float a = 0.f, bb = 0.f;
#pragma unroll
      for (int g = 0; g < 8; ++g) { a += ls[g][tid]; bb += ls2[g][tid]; }
      part_s[b * DIN + tid] = a;
      part_s2[b * DIN + tid] = bb;
    }
  } else if (b < 256) {
    int idx = (b - 64) * 256 + tid;        // [0, 49152)
    int k = idx / 384, c = idx % 384;
    Wc[idx] = (c < 256) ? Wt[(size_t)c * DIN + k] : Wo[(size_t)(c - 256) * DIN + k];
  } else if (b < 258) {
    int c = (b - 256) * 256 + tid;
    if (c < 384) bc[c] = (c < 256) ? bt[c] : bo[c - 256];
  } else {
    int g = (b - 258) * 256 + tid;         // [0, 4096) int4 = 64 KB
    ((int4*)deg)[g] = make_int4(0, 0, 0, 0);
  }
}

// ---------------- K2: GEMM blocks + A3-zero blocks -----------------------
// blocks [0,512): Hxh(bf16)/HW/sq for 16 rows each (BN finalize inlined);
// blocks [512, 512+8192): zero A3 row (b-512) with nontemporal stores.
__global__ __launch_bounds__(256) void k_rows(
    const float* __restrict__ H,
    const float* __restrict__ part_s, const float* __restrict__ part_s2,
    const float* __restrict__ gamma, const float* __restrict__ beta,
    const float* __restrict__ Wc, const float* __restrict__ bc,
    unsigned short* __restrict__ Hxh, float* __restrict__ HW,
    float* __restrict__ sq, float* __restrict__ A3) {
  int tid = threadIdx.x;
  int b = blockIdx.x;
  if (b >= 512) {
    vfloat4* row = (vfloat4*)(A3 + (size_t)(b - 512) * N);
    const vfloat4 z = {0.f, 0.f, 0.f, 0.f};
#pragma unroll
    for (int it = 0; it < 8; ++it)
      __builtin_nontemporal_store(z, row + tid + it * 256);
    return;
  }
  __shared__ __align__(16) float ssc[DIN];
  __shared__ __align__(16) float ssh[DIN];
  __shared__ float hn[16][DIN];   // 8 KB; reads below are wave-broadcast
  // inline BN finalize (identical bit-exact result in every block)
  if (tid < DIN) {
    float s = 0.f, s2 = 0.f;
    for (int g = 0; g < 64; ++g) { s += part_s[g*DIN+tid]; s2 += part_s2[g*DIN+tid]; }
    float mean = s * (1.0f / N);
    float var  = s2 * (1.0f / N) - mean * mean;
    float sc = rsqrtf(var + 1e-5f) * gamma[tid];
    ssc[tid] = sc;
    ssh[tid] = beta[tid] - mean * sc;
  }
  __syncthreads();
  int base = b * 16;
#pragma unroll
  for (int k = 0; k < 2; ++k) {
    int f = tid + k * 256;
    int r = f >> 5, c4 = f & 31;
    float4 h  = ((const float4*)(H + (size_t)(base + r) * DIN))[c4];
    float4 sc = ((const float4*)ssc)[c4];
    float4 sh = ((const float4*)ssh)[c4];
    h.x = h.x * sc.x + sh.x; h.y = h.y * sc.y + sh.y;
    h.z = h.z * sc.z + sh.z; h.w = h.w * sc.w + sh.w;
    ((float4*)hn[r])[c4] = h;
  }
  __syncthreads();
  int w = tid >> 6, lane = tid & 63;
  int r0 = w * 4;
  float acc[4][6];
#pragma unroll
  for (int r = 0; r < 4; ++r)
#pragma unroll
    for (int q = 0; q < 6; ++q) acc[r][q] = 0.f;

  for (int k4 = 0; k4 < 32; ++k4) {
    float4 h[4];
#pragma unroll
    for (int r = 0; r < 4; ++r) h[r] = ((const float4*)hn[r0 + r])[k4];
#pragma unroll
    for (int kk = 0; kk < 4; ++kk) {
      const float* wrow = Wc + (size_t)(k4 * 4 + kk) * 384 + lane;
      float wv[6];
#pragma unroll
      for (int q = 0; q < 6; ++q) wv[q] = wrow[64 * q];
#pragma unroll
      for (int r = 0; r < 4; ++r) {
        float hs = (kk == 0) ? h[r].x : (kk == 1) ? h[r].y
                 : (kk == 2) ? h[r].z : h[r].w;
#pragma unroll
        for (int q = 0; q < 6; ++q) acc[r][q] += hs * wv[q];
      }
    }
  }
#pragma unroll
  for (int r = 0; r < 4; ++r) {
    int row = base + r0 + r;
    float s = 0.f;
#pragma unroll
    for (int q = 0; q < 4; ++q) {
      float v = acc[r][q] + bc[lane + 64 * q];
      Hxh[(size_t)row * DTH + lane + 64 * q] = f2bf(v);
      s += v * v;
    }
#pragma unroll
    for (int off = 32; off > 0; off >>= 1) s += __shfl_xor(s, off, 64);
    if (lane == 0) sq[row] = s;
#pragma unroll
    for (int q = 4; q < 6; ++q) {
      float v = acc[r][q] + bc[lane + 64 * q];
      HW[(size_t)row * DOUT + lane + 64 * (q - 4)] = v;
    }
  }
}

// ---------------- K3: upper-tri edge pass, direct A3 scatter -------------
// A3 rows are fully zeroed by k_rows (previous kernel in stream) before any
// block here runs, so scattered writes of survivors are safe.
__global__ __launch_bounds__(256) void k_main(
    const float* __restrict__ A_adj, const unsigned short* __restrict__ Hxh,
    const float* __restrict__ sq, float* __restrict__ A3,
    float* __restrict__ deg, int* __restrict__ nnz_cnt,
    int* __restrict__ nnz_idx, float* __restrict__ nnz_val) {
  int i = blockIdx.x;
  int tid = threadIdx.x;
  __shared__ float4 hx4[64];          // hx_i as 64 float4
  __shared__ int   s_list[LISTCAP];
  __shared__ int   s_cnt;
  if (tid == 0) s_cnt = 0;
  ((float*)hx4)[tid] = __uint_as_float(((uint32_t)Hxh[(size_t)i * DTH + tid]) << 16);
  __syncthreads();

  const vfloat4* arow = (const vfloat4*)(A_adj + (size_t)i * N);
  int q0 = i >> 2;
  for (int q4 = q0 + tid; q4 < N / 4; q4 += 256) {
    vfloat4 a = __builtin_nontemporal_load(arow + q4);
    int jb = q4 * 4;
    float av[4] = {a.x, a.y, a.z, a.w};
#pragma unroll
    for (int q = 0; q < 4; ++q) {
      int j = jb + q;
      if (av[q] != 0.f && j >= i) {
        int p = atomicAdd(&s_cnt, 1);
        if (p < LISTCAP) s_list[p] = j;
      }
    }
  }
  __syncthreads();

  int M = min(s_cnt, LISTCAP);
  float sqi = sq[i];
  for (int t = tid; t < M; t += 256) {
    int j = s_list[t];
    bool keep = dropedge_keep((uint32_t)i * (uint32_t)N + (uint32_t)j);
    float dist;
    if (j == i) {
      dist = 1e-6f;                      // exact diagonal: sqrt(clip(0,1e-12))
    } else {
      const uint4* hj = (const uint4*)(Hxh + (size_t)j * DTH);
      float dot = 0.f;
#pragma unroll 8
      for (int c = 0; c < 32; ++c) {
        uint4 u = hj[c];
        float4 f0 = hx4[2 * c], f1 = hx4[2 * c + 1];
        dot += __uint_as_float(u.x << 16) * f0.x
             + __uint_as_float(u.x & 0xffff0000u) * f0.y
             + __uint_as_float(u.y << 16) * f0.z
             + __uint_as_float(u.y & 0xffff0000u) * f0.w
             + __uint_as_float(u.z << 16) * f1.x
             + __uint_as_float(u.z & 0xffff0000u) * f1.y
             + __uint_as_float(u.w << 16) * f1.z
             + __uint_as_float(u.w & 0xffff0000u) * f1.w;
      }
      dist = sqrtf(fmaxf(sqi + sq[j] - 2.0f * dot, 1e-12f));
    }
    float aval = expf(-0.2f * dist);
    float sg = fmaxf(1.0f / (1.0f + expf(-aval)), 0.1f);
    float bb = keep ? sg : 0.0f;
    float a2 = bb + ((i == j) ? 1.0f : 0.0f);
    float a3v = (a2 > 0.6f) ? a2 : 0.0f;
    if (a3v != 0.f) {
      A3[(size_t)i * N + j] = a3v;
      atomicAdd(&deg[i], a3v);
      int p = atomicAdd(&nnz_cnt[i], 1);
      if (p < ROWCAP) {
        nnz_idx[(size_t)i * ROWCAP + p] = j;
        nnz_val[(size_t)i * ROWCAP + p] = a3v;
      }
      if (j != i) {
        A3[(size_t)j * N + i] = a3v;
        atomicAdd(&deg[j], a3v);
        int p2 = atomicAdd(&nnz_cnt[j], 1);
        if (p2 < ROWCAP) {
          nnz_idx[(size_t)j * ROWCAP + p2] = i;
          nnz_val[(size_t)j * ROWCAP + p2] = a3v;
        }
      }
    }
  }
}

// ---------------- K4: out = lrelu(D^-1/2 A3 D^-1/2 @ HW) -----------------
__global__ __launch_bounds__(128) void k_post(
    const float* __restrict__ HW, const float* __restrict__ deg,
    const int* __restrict__ nnz_cnt, const int* __restrict__ nnz_idx,
    const float* __restrict__ nnz_val, float* __restrict__ out) {
  int i = blockIdx.x;
  int c = threadIdx.x;      // 128
  int cnt = min(nnz_cnt[i], ROWCAP);
  float acc = 0.f;
  for (int e = 0; e < cnt; ++e) {
    int j = nnz_idx[(size_t)i * ROWCAP + e];
    float v = nnz_val[(size_t)i * ROWCAP + e];
    acc += v * rsqrtf(deg[j]) * HW[(size_t)j * DOUT + c];
  }
  float o = rsqrtf(deg[i]) * acc;
  out[(size_t)i * DOUT + c] = (o >= 0.f) ? o : 0.01f * o;
}

// ---------------- launch --------------------------------------------------
extern "C" void kernel_launch(void* const* d_in, const int* in_sizes, int n_in,
                              void* d_out, int out_size, void* d_ws, size_t ws_size,
                              hipStream_t stream) {
  const float* H     = (const float*)d_in[0];
  const float* A_adj = (const float*)d_in[1];
  const float* gamma = (const float*)d_in[2];
  const float* beta  = (const float*)d_in[3];
  const float* Wt    = (const float*)d_in[4];
  const float* bt    = (const float*)d_in[5];
  const float* Wo    = (const float*)d_in[6];
  const float* bo    = (const float*)d_in[7];

  float* out = (float*)d_out;                    // [N, DOUT]
  float* A3  = out + (size_t)N * DOUT;           // [N, N]

  float* ws    = (float*)d_ws;
  unsigned short* Hxh = (unsigned short*)ws;      // N*256 bf16 (= N*128 floats)
  float* sq    = ws + (size_t)N * 128;            // N
  float* HW    = sq + N;                          // N*128
  float* deg   = HW + (size_t)N * DOUT;           // N   (deg+cnt contiguous!)
  int*   nnz_cnt = (int*)(deg + N);               // N
  int*   nnz_idx = nnz_cnt + N;                   // N*ROWCAP
  float* nnz_val = (float*)(nnz_idx + (size_t)N * ROWCAP); // N*ROWCAP
  float* part_s  = nnz_val + (size_t)N * ROWCAP;  // 64*128
  float* part_s2 = part_s + 64 * DIN;             // 64*128
  float* Wc      = part_s2 + 64 * DIN;            // 128*384
  float* bc      = Wc + 128 * 384;                // 384

  k_pre<<<274, 256, 0, stream>>>(H, Wt, bt, Wo, bo, part_s, part_s2, Wc, bc, deg);
  k_rows<<<512 + N, 256, 0, stream>>>(H, part_s, part_s2, gamma, beta, Wc, bc,
                                      Hxh, HW, sq, A3);
  k_main<<<N, 256, 0, stream>>>(A_adj, Hxh, sq, A3, deg, nnz_cnt, nnz_idx, nnz_val);
  k_post<<<N, DOUT, 0, stream>>>(HW, deg, nnz_cnt, nnz_idx, nnz_val, out);
}